// Round 4
// baseline (394.240 us; speedup 1.0000x reference)
//
#include <hip/hip_runtime.h>

// ---------------------------------------------------------------------------
// SelfAttention: B=2,T=2048,D_IN=1024,E=64,H=16, causal, interleaved (E,H)
// Barrier-free design:
//   gemm_qkv: one 4096x3072 GEMM, direct-global register fragments, reg dbuf.
//   attn: S^T orientation (softmax in-lane), K/V frags direct from global,
//         per-wave P^T LDS round-trip only. No __syncthreads anywhere hot.
// Layouts: qh/kh [b][t][h*64+e] (Wt rows permuted), vh [b][h][e][t],
//          ot [b][t][h*64+e] with Wu k-rows permuted to match.
// ---------------------------------------------------------------------------

typedef __bf16 bf16x8 __attribute__((ext_vector_type(8)));
typedef float f32x4 __attribute__((ext_vector_type(4)));
typedef unsigned short u16;
typedef unsigned int u32;

__device__ __forceinline__ u16 f2bf(float f) {
    union { float f; u32 u; } v; v.f = f;
    u32 r = (v.u + 0x7FFFu + ((v.u >> 16) & 1u)) >> 16;   // RNE
    return (u16)r;
}

#define MM 4096           // B*T
#define SCALE_LOG2E 0.18033688011112042f   // log2(e)/sqrt(64)

// ---------------- kernel 1: cast inp -> bf16 ----------------
__global__ void cast_x(const float* __restrict__ in, u16* __restrict__ out, int n4) {
    int i = blockIdx.x * blockDim.x + threadIdx.x;
    if (i < n4) {
        float4 f = ((const float4*)in)[i];
        ushort4 o;
        o.x = f2bf(f.x); o.y = f2bf(f.y); o.z = f2bf(f.z); o.w = f2bf(f.w);
        ((ushort4*)out)[i] = o;
    }
}

// ---------------- kernel 2: W[k][n] fp32 -> Wt bf16 (permuted) ----------------
// Wq/Wk/Wv (n = e*16+h): row perm(n) = h*64+e.  Wu: k-col perm(k) = (k&15)*64+(k>>4).
__global__ void transpose_w(const float* __restrict__ Wq, const float* __restrict__ Wk,
                            const float* __restrict__ Wv, const float* __restrict__ Wu,
                            u16* __restrict__ wqt, u16* __restrict__ wkt,
                            u16* __restrict__ wvt, u16* __restrict__ wut) {
    int z = blockIdx.z;
    const float* src; u16* dst; int N;
    if (z == 0)      { src = Wq; dst = wqt; N = 1024; }
    else if (z == 1) { src = Wk; dst = wkt; N = 1024; }
    else if (z == 2) { src = Wv; dst = wvt; N = 1024; }
    else             { src = Wu; dst = wut; N = 64; if (blockIdx.y >= 2) return; }
    __shared__ float lds[32][33];
    int k0 = blockIdx.x * 32, n0 = blockIdx.y * 32;
    int tid = threadIdx.x;
    int c = tid & 31, r0 = tid >> 5;
#pragma unroll
    for (int p = 0; p < 4; ++p) {
        int r = r0 + p * 8;
        lds[r][c] = src[(k0 + r) * N + n0 + c];
    }
    __syncthreads();
#pragma unroll
    for (int p = 0; p < 4; ++p) {
        int n = n0 + r0 + p * 8;
        if (z < 3) {
            int rnew = ((n & 15) << 6) | (n >> 4);
            dst[rnew * 1024 + k0 + c] = f2bf(lds[c][n - n0]);
        } else {
            int k = k0 + c;
            int kp = ((k & 15) << 6) | (k >> 4);
            dst[n * 1024 + kp] = f2bf(lds[c][n - n0]);
        }
    }
}

// ---------------- kernel 3: fused QKV GEMM, barrier-free ----------------
// C[4096,3072] = Xb[4096,1024] * W3[3072,1024]^T; 128x128 tiles, direct-global
// register fragments, double-buffered. Epilogue routes by n-range:
//   n<1024: Q *SCALE -> [b][t][h*64+e]; <2048: K same; else V -> [b][h][e][t].
__global__ __launch_bounds__(256, 3) void gemm_qkv(const u16* __restrict__ xb,
                                                   const u16* __restrict__ w3,
                                                   u16* __restrict__ qh, u16* __restrict__ kh,
                                                   u16* __restrict__ vh) {
    int tid = threadIdx.x;
    int lane = tid & 63, w = tid >> 6;
    int wr = w >> 1, wc = w & 1;
    int l15 = lane & 15, quad = lane >> 4;
    int n0 = blockIdx.x * 128, m0 = blockIdx.y * 128;
    const u16* arow = xb + (m0 + wr * 64 + l15) * 1024 + quad * 8;   // +i*16*1024 +kb
    const u16* brow = w3 + (n0 + wc * 64 + l15) * 1024 + quad * 8;   // +j*16*1024 +kb
    f32x4 acc[4][4] = {};
    bf16x8 af[2][4], bf[2][4];
#pragma unroll
    for (int i = 0; i < 4; ++i) {
        af[0][i] = *(const bf16x8*)(arow + i * 16384);
        bf[0][i] = *(const bf16x8*)(brow + i * 16384);
    }
#pragma unroll 2
    for (int kk = 0; kk < 32; ++kk) {
        int cur = kk & 1;
        if (kk < 31) {
            int kb = (kk + 1) * 32;
#pragma unroll
            for (int i = 0; i < 4; ++i) {
                af[cur ^ 1][i] = *(const bf16x8*)(arow + i * 16384 + kb);
                bf[cur ^ 1][i] = *(const bf16x8*)(brow + i * 16384 + kb);
            }
        }
#pragma unroll
        for (int i = 0; i < 4; ++i)
#pragma unroll
            for (int j = 0; j < 4; ++j)
                acc[i][j] = __builtin_amdgcn_mfma_f32_16x16x32_bf16(af[cur][i], bf[cur][j], acc[i][j], 0, 0, 0);
    }
    int z = n0 >> 10;
    int h = ((n0 & 1023) >> 6) + wc;
    int bb = m0 >> 11;
    if (z < 2) {
        u16* dst = (z == 0) ? qh : kh;
        float scale = (z == 0) ? SCALE_LOG2E : 1.f;
#pragma unroll
        for (int i = 0; i < 4; ++i)
#pragma unroll
            for (int j = 0; j < 4; ++j)
#pragma unroll
                for (int r = 0; r < 4; ++r) {
                    int m = m0 + wr * 64 + i * 16 + quad * 4 + r;
                    dst[m * 1024 + h * 64 + j * 16 + l15] = f2bf(acc[i][j][r] * scale);
                }
    } else {
#pragma unroll
        for (int i = 0; i < 4; ++i)
#pragma unroll
            for (int j = 0; j < 4; ++j) {
                int t4 = (m0 & 2047) + wr * 64 + i * 16 + quad * 4;
                ushort4 o;
                o.x = f2bf(acc[i][j][0]); o.y = f2bf(acc[i][j][1]);
                o.z = f2bf(acc[i][j][2]); o.w = f2bf(acc[i][j][3]);
                *(ushort4*)(vh + (((bb * 16 + h) * 64) + j * 16 + l15) * 2048 + t4) = o;
            }
    }
}

// ---------------- kernel 4: flash attention, barrier-free ----------------
// grid (32 heads, 16 pairs) x 256. Each wave owns a 16-row t-strip; computes
// S^T = K Q^T (softmax in-lane + 2 shuffles), O^T = V^T P^T. K/V frags direct
// from global (K reg-dbuf, V issued early); P^T via per-wave LDS only.
__global__ __launch_bounds__(256, 2) void attn(const u16* __restrict__ qh, const u16* __restrict__ kh,
                                               const u16* __restrict__ vh, u16* __restrict__ ot) {
    __shared__ u16 sP[4 * 16 * 72];    // per-wave 16 x 72 (9216 B total)
    const int tid = threadIdx.x;
    const int lane = tid & 63, w = tid >> 6;
    const int quad = lane >> 4, l15 = lane & 15;
    const int by = blockIdx.x;          // head-major for XCD L2 locality
    const int p = blockIdx.y;
    const int b = by >> 4, h = by & 15;
    const u16* qb = qh + (b * 2048) * 1024 + h * 64;
    const u16* kb = kh + (b * 2048) * 1024 + h * 64;
    const u16* vb = vh + (by * 64) * 2048;
    u16* sPw = sP + w * 16 * 72;
    const int tl = w * 16 + l15;        // strip-local t for this lane

    for (int hv = 0; hv < 2; ++hv) {
        const int qt = hv ? p : 31 - p;
        const int tg = qt * 64 + tl;    // global t (col owned by this lane)
        bf16x8 aq[2];
        aq[0] = *(const bf16x8*)(qb + tg * 1024 + quad * 8);
        aq[1] = *(const bf16x8*)(qb + tg * 1024 + 32 + quad * 8);
        f32x4 oacc[4] = {};
        float mrow = -3e38f, lrow = 0.f;
        bf16x8 ak[2][4][2];
#pragma unroll
        for (int j4 = 0; j4 < 4; ++j4)
#pragma unroll
            for (int k2 = 0; k2 < 2; ++k2)
                ak[0][j4][k2] = *(const bf16x8*)(kb + (j4 * 16 + l15) * 1024 + k2 * 32 + quad * 8);
        for (int jt = 0; jt <= qt; ++jt) {
            const int cur = jt & 1;
            bf16x8 av[4][2];
#pragma unroll
            for (int e4 = 0; e4 < 4; ++e4)
#pragma unroll
                for (int k2 = 0; k2 < 2; ++k2)
                    av[e4][k2] = *(const bf16x8*)(vb + (e4 * 16 + l15) * 2048 + jt * 64 + k2 * 32 + quad * 8);
            if (jt < qt) {              // prefetch next K tile into alternate buffer
                const u16* kn = kb + (jt + 1) * 65536;
#pragma unroll
                for (int j4 = 0; j4 < 4; ++j4)
#pragma unroll
                    for (int k2 = 0; k2 < 2; ++k2)
                        ak[cur ^ 1][j4][k2] = *(const bf16x8*)(kn + (j4 * 16 + l15) * 1024 + k2 * 32 + quad * 8);
            }
            f32x4 sacc[4] = {};
#pragma unroll
            for (int j4 = 0; j4 < 4; ++j4)
#pragma unroll
                for (int k2 = 0; k2 < 2; ++k2)
                    sacc[j4] = __builtin_amdgcn_mfma_f32_16x16x32_bf16(ak[cur][j4][k2], aq[k2], sacc[j4], 0, 0, 0);
            if (jt == qt) {             // diagonal: causal mask, s > t -> -inf
#pragma unroll
                for (int j4 = 0; j4 < 4; ++j4)
#pragma unroll
                    for (int r = 0; r < 4; ++r)
                        if (j4 * 16 + quad * 4 + r > tl) sacc[j4][r] = -1e30f;
            }
            // online softmax: each lane owns col t; 16 s-values in-lane + quad butterfly
            float mx = -3e38f;
#pragma unroll
            for (int j4 = 0; j4 < 4; ++j4)
#pragma unroll
                for (int r = 0; r < 4; ++r) mx = fmaxf(mx, sacc[j4][r]);
            mx = fmaxf(mx, __shfl_xor(mx, 16));
            mx = fmaxf(mx, __shfl_xor(mx, 32));
            float mnew = fmaxf(mrow, mx);
            float alpha = __builtin_amdgcn_exp2f(mrow - mnew);
            float rs = 0.f;
#pragma unroll
            for (int j4 = 0; j4 < 4; ++j4)
#pragma unroll
                for (int r = 0; r < 4; ++r) {
                    float pe = __builtin_amdgcn_exp2f(sacc[j4][r] - mnew);
                    sacc[j4][r] = pe; rs += pe;
                }
            rs += __shfl_xor(rs, 16);
            rs += __shfl_xor(rs, 32);
            lrow = lrow * alpha + rs;
            mrow = mnew;
#pragma unroll
            for (int e4 = 0; e4 < 4; ++e4) {
                oacc[e4][0] *= alpha; oacc[e4][1] *= alpha;
                oacc[e4][2] *= alpha; oacc[e4][3] *= alpha;
            }
            // P^T: pack 4 contiguous s per (j4) -> per-wave LDS, read back as B-frag
#pragma unroll
            for (int j4 = 0; j4 < 4; ++j4) {
                ushort4 o;
                o.x = f2bf(sacc[j4][0]); o.y = f2bf(sacc[j4][1]);
                o.z = f2bf(sacc[j4][2]); o.w = f2bf(sacc[j4][3]);
                *(ushort4*)(sPw + l15 * 72 + j4 * 16 + quad * 4) = o;
            }
            bf16x8 bp[2];
            bp[0] = *(const bf16x8*)(sPw + l15 * 72 + quad * 8);
            bp[1] = *(const bf16x8*)(sPw + l15 * 72 + 32 + quad * 8);
#pragma unroll
            for (int e4 = 0; e4 < 4; ++e4)
#pragma unroll
                for (int k2 = 0; k2 < 2; ++k2)
                    oacc[e4] = __builtin_amdgcn_mfma_f32_16x16x32_bf16(av[e4][k2], bp[k2], oacc[e4], 0, 0, 0);
        }
        // epilogue: O^T col = t (lane), rows e contiguous in r -> ushort4 stores
        float inv = 1.f / lrow;
        u16* orow = ot + (b * 2048 + tg) * 1024 + h * 64;
#pragma unroll
        for (int e4 = 0; e4 < 4; ++e4) {
            ushort4 o;
            o.x = f2bf(oacc[e4][0] * inv); o.y = f2bf(oacc[e4][1] * inv);
            o.z = f2bf(oacc[e4][2] * inv); o.w = f2bf(oacc[e4][3] * inv);
            *(ushort4*)(orow + e4 * 16 + quad * 4) = o;
        }
    }
}

// ---------------- kernel 5: out = ot[M,1024] @ Wu + bu ----------------
// 256 blocks x 16 rows; 4 waves split K (256 each); direct 16B frag loads, LDS reduce.
__global__ __launch_bounds__(256) void gemm_out(const u16* __restrict__ ot, const u16* __restrict__ wut,
                                                const float* __restrict__ bu, float* __restrict__ out) {
    __shared__ float red[4][1088];     // [w][n*17 + m]
    int tid = threadIdx.x, lane = tid & 63, w = tid >> 6;
    int quad = lane >> 4, l15 = lane & 15;
    int m0 = blockIdx.x * 16;
    f32x4 acc[4] = {};
    const u16* aptr = ot + (m0 + l15) * 1024 + w * 256 + quad * 8;
    const u16* bptr = wut + l15 * 1024 + w * 256 + quad * 8;
#pragma unroll
    for (int kk = 0; kk < 8; ++kk) {
        bf16x8 af = *(const bf16x8*)(aptr + kk * 32);
#pragma unroll
        for (int j = 0; j < 4; ++j) {
            bf16x8 bfr = *(const bf16x8*)(bptr + j * 16 * 1024 + kk * 32);
            acc[j] = __builtin_amdgcn_mfma_f32_16x16x32_bf16(af, bfr, acc[j], 0, 0, 0);
        }
    }
#pragma unroll
    for (int j = 0; j < 4; ++j)
#pragma unroll
        for (int r = 0; r < 4; ++r)
            red[w][(j * 16 + l15) * 17 + quad * 4 + r] = acc[j][r];
    __syncthreads();
    int n = tid & 63, mq = tid >> 6;
    float bias = bu[n];
#pragma unroll
    for (int i = 0; i < 4; ++i) {
        int m = mq * 4 + i;
        float s = red[0][n * 17 + m] + red[1][n * 17 + m] + red[2][n * 17 + m] + red[3][n * 17 + m];
        out[(m0 + m) * 64 + n] = s + bias;
    }
}

// ---------------- workspace layout (bytes) ----------------
#define OFF_XB   0u          /* 8 MB; ot aliases this (xb dead after gemm_qkv) */
#define OFF_WQT  8388608u    /* 2 MB; wqt/wkt/wvt contiguous = W3[3072][1024] */
#define OFF_WKT  10485760u
#define OFF_WVT  12582912u
#define OFF_WUT  14680064u   /* 128 KB */
#define OFF_QH   14811136u   /* 8 MB each */
#define OFF_KH   23199744u
#define OFF_VH   31588352u
#define OFF_OT   OFF_XB

extern "C" void kernel_launch(void* const* d_in, const int* in_sizes, int n_in,
                              void* d_out, int out_size, void* d_ws, size_t ws_size,
                              hipStream_t stream) {
    (void)in_sizes; (void)n_in; (void)out_size; (void)ws_size;
    const float* inp = (const float*)d_in[0];
    // d_in[1] = causal mask — implemented analytically
    const float* Wq = (const float*)d_in[2];
    const float* Wk = (const float*)d_in[3];
    const float* Wv = (const float*)d_in[4];
    const float* Wu = (const float*)d_in[5];
    const float* bu = (const float*)d_in[6];
    float* out = (float*)d_out;
    char* ws = (char*)d_ws;
    u16* xb  = (u16*)(ws + OFF_XB);
    u16* wqt = (u16*)(ws + OFF_WQT);
    u16* wkt = (u16*)(ws + OFF_WKT);
    u16* wvt = (u16*)(ws + OFF_WVT);
    u16* wut = (u16*)(ws + OFF_WUT);
    u16* qh  = (u16*)(ws + OFF_QH);
    u16* kh  = (u16*)(ws + OFF_KH);
    u16* vh  = (u16*)(ws + OFF_VH);
    u16* ot  = (u16*)(ws + OFF_OT);

    cast_x<<<4096, 256, 0, stream>>>(inp, xb, (MM * 1024) / 4);
    transpose_w<<<dim3(32, 32, 4), 256, 0, stream>>>(Wq, Wk, Wv, Wu, wqt, wkt, wvt, wut);
    gemm_qkv<<<dim3(24, 32), 256, 0, stream>>>(xb, wqt, qh, kh, vh);
    attn<<<dim3(32, 16), 256, 0, stream>>>(qh, kh, vh, ot);
    gemm_out<<<256, 256, 0, stream>>>(ot, wut, bu, out);
}

// Round 5
// 221.797 us; speedup vs baseline: 1.7775x; 1.7775x over previous
//
#include <hip/hip_runtime.h>

// ---------------------------------------------------------------------------
// SelfAttention: B=2,T=2048,D_IN=1024,E=64,H=16, causal, interleaved (E,H)
// R5: r3 LDS-staged skeleton + r4 S^T in-lane softmax (no spills, no redundant
// K/V loads). gemm_qkv merged 4096x3072, m97-style staging, operand-swapped
// MFMA for Q/K so epilogue stores are packed ushort4.
// Layouts: qh/kh [b][t][h*64+e], vh [b][h][e][t], ot [b][t][h*64+e] (Wu k-perm).
// ---------------------------------------------------------------------------

typedef __bf16 bf16x8 __attribute__((ext_vector_type(8)));
typedef float f32x4 __attribute__((ext_vector_type(4)));
typedef unsigned short u16;
typedef unsigned int u32;

#define AS1 __attribute__((address_space(1)))
#define AS3 __attribute__((address_space(3)))

__device__ __forceinline__ void gll16(const void* g, void* l) {
    __builtin_amdgcn_global_load_lds((const AS1 u32*)g, (AS3 u32*)l, 16, 0, 0);
}

__device__ __forceinline__ u16 f2bf(float f) {
    union { float f; u32 u; } v; v.f = f;
    u32 r = (v.u + 0x7FFFu + ((v.u >> 16) & 1u)) >> 16;   // RNE
    return (u16)r;
}

#define MM 4096           // B*T
#define SCALE_LOG2E 0.18033688011112042f   // log2(e)/sqrt(64)

// ---------------- kernel 1: cast inp -> bf16 ----------------
__global__ void cast_x(const float* __restrict__ in, u16* __restrict__ out, int n4) {
    int i = blockIdx.x * blockDim.x + threadIdx.x;
    if (i < n4) {
        float4 f = ((const float4*)in)[i];
        ushort4 o;
        o.x = f2bf(f.x); o.y = f2bf(f.y); o.z = f2bf(f.z); o.w = f2bf(f.w);
        ((ushort4*)out)[i] = o;
    }
}

// ---------------- kernel 2: W[k][n] fp32 -> Wt bf16 (permuted) ----------------
// Wq/Wk/Wv (n = e*16+h): row perm(n) = h*64+e.  Wu: k-col perm(k) = (k&15)*64+(k>>4).
__global__ void transpose_w(const float* __restrict__ Wq, const float* __restrict__ Wk,
                            const float* __restrict__ Wv, const float* __restrict__ Wu,
                            u16* __restrict__ wqt, u16* __restrict__ wkt,
                            u16* __restrict__ wvt, u16* __restrict__ wut) {
    int z = blockIdx.z;
    const float* src; u16* dst; int N;
    if (z == 0)      { src = Wq; dst = wqt; N = 1024; }
    else if (z == 1) { src = Wk; dst = wkt; N = 1024; }
    else if (z == 2) { src = Wv; dst = wvt; N = 1024; }
    else             { src = Wu; dst = wut; N = 64; if (blockIdx.y >= 2) return; }
    __shared__ float lds[32][33];
    int k0 = blockIdx.x * 32, n0 = blockIdx.y * 32;
    int tid = threadIdx.x;
    int c = tid & 31, r0 = tid >> 5;
#pragma unroll
    for (int p = 0; p < 4; ++p) {
        int r = r0 + p * 8;
        lds[r][c] = src[(k0 + r) * N + n0 + c];
    }
    __syncthreads();
#pragma unroll
    for (int p = 0; p < 4; ++p) {
        int n = n0 + r0 + p * 8;
        if (z < 3) {
            int rnew = ((n & 15) << 6) | (n >> 4);
            dst[rnew * 1024 + k0 + c] = f2bf(lds[c][n - n0]);
        } else {
            int k = k0 + c;
            int kp = ((k & 15) << 6) | (k >> 4);
            dst[n * 1024 + kp] = f2bf(lds[c][n - n0]);
        }
    }
}

// ---------------- kernel 3: fused QKV GEMM (m97-style LDS staging) ----------------
// C[4096,3072] = Xb * W3^T. n-tile: x<8 -> Q (*SCALE), <16 -> K, else V.
// Q/K: operand-swapped MFMA (D[n][m]) so n packs in regs -> ushort4 stores.
__global__ __launch_bounds__(256, 3) void gemm_qkv(const u16* __restrict__ xb,
                                                   const u16* __restrict__ w3,
                                                   u16* __restrict__ qh, u16* __restrict__ kh,
                                                   u16* __restrict__ vh) {
    __shared__ u16 lA[128 * 32];
    __shared__ u16 lB[128 * 32];
    int tid = threadIdx.x;
    int n0 = blockIdx.x * 128, m0 = blockIdx.y * 128;
    int z = n0 >> 10;
    int lane = tid & 63, w = tid >> 6;
    int wr = w >> 1, wc = w & 1;
    int l15 = lane & 15, quad = lane >> 4;
    f32x4 acc[4][4] = {};
    int srow = tid >> 2, scol = (tid & 3) * 8;
#pragma unroll 1
    for (int kk = 0; kk < 32; ++kk) {
        int kb = kk * 32;
        __syncthreads();
#pragma unroll
        for (int pp = 0; pp < 2; ++pp) {
            gll16(xb + (m0 + pp * 64 + srow) * 1024 + kb + scol, lA + (pp * 256 + tid) * 8);
            gll16(w3 + (n0 + pp * 64 + srow) * 1024 + kb + scol, lB + (pp * 256 + tid) * 8);
        }
        __syncthreads();
        bf16x8 af[4], bfr[4];
#pragma unroll
        for (int i = 0; i < 4; ++i)
            af[i] = *(const bf16x8*)(lA + (wr * 64 + i * 16 + l15) * 32 + quad * 8);
#pragma unroll
        for (int j = 0; j < 4; ++j)
            bfr[j] = *(const bf16x8*)(lB + (wc * 64 + j * 16 + l15) * 32 + quad * 8);
        if (z < 2) {   // D[n][m]: rows n (packed in regs), cols m (lane)
#pragma unroll
            for (int i = 0; i < 4; ++i)
#pragma unroll
                for (int j = 0; j < 4; ++j)
                    acc[i][j] = __builtin_amdgcn_mfma_f32_16x16x32_bf16(bfr[j], af[i], acc[i][j], 0, 0, 0);
        } else {       // D[m][n]: rows m (t packed in regs), cols n (lane)
#pragma unroll
            for (int i = 0; i < 4; ++i)
#pragma unroll
                for (int j = 0; j < 4; ++j)
                    acc[i][j] = __builtin_amdgcn_mfma_f32_16x16x32_bf16(af[i], bfr[j], acc[i][j], 0, 0, 0);
        }
    }
    int h = ((n0 & 1023) >> 6) + wc;
    int bb = m0 >> 11;
    if (z < 2) {
        u16* dst = (z == 0) ? qh : kh;
        float scale = (z == 0) ? SCALE_LOG2E : 1.f;
#pragma unroll
        for (int i = 0; i < 4; ++i) {
            int m = m0 + wr * 64 + i * 16 + l15;
#pragma unroll
            for (int j = 0; j < 4; ++j) {
                ushort4 o;
                o.x = f2bf(acc[i][j][0] * scale); o.y = f2bf(acc[i][j][1] * scale);
                o.z = f2bf(acc[i][j][2] * scale); o.w = f2bf(acc[i][j][3] * scale);
                *(ushort4*)(dst + m * 1024 + h * 64 + j * 16 + quad * 4) = o;
            }
        }
    } else {
#pragma unroll
        for (int i = 0; i < 4; ++i)
#pragma unroll
            for (int j = 0; j < 4; ++j) {
                int t4 = (m0 & 2047) + wr * 64 + i * 16 + quad * 4;
                ushort4 o;
                o.x = f2bf(acc[i][j][0]); o.y = f2bf(acc[i][j][1]);
                o.z = f2bf(acc[i][j][2]); o.w = f2bf(acc[i][j][3]);
                *(ushort4*)(vh + (((bb * 16 + h) * 64) + j * 16 + l15) * 2048 + t4) = o;
            }
    }
}

// ---------------- kernel 4: flash attention (S^T, LDS-staged K/V) ----------------
// grid (32 heads, 16 pairs) x 256 (4 waves x 16 t-cols). Block p: qtiles 31-p, p.
// S^T = K Q^T -> softmax in-lane (2+2 shuffles) -> O^T = V^T P^T.
__global__ __launch_bounds__(256, 2) void attn(const u16* __restrict__ qh, const u16* __restrict__ kh,
                                               const u16* __restrict__ vh, u16* __restrict__ ot) {
    __shared__ u16 sK[4096];           // [e2][64 s][32 e] (8 KB)
    __shared__ u16 sV[4096];           // [s2][64 e][32 s] (8 KB)
    __shared__ u16 sP[4 * 16 * 72];    // per-wave P^T strip [t16][72] (9.2 KB)
    const int tid = threadIdx.x;
    const int lane = tid & 63, w = tid >> 6;
    const int quad = lane >> 4, l15 = lane & 15;
    const int by = blockIdx.x;          // head on x: all 16 blocks of a head -> same XCD
    const int p = blockIdx.y;
    const int b = by >> 4, h = by & 15;
    const u16* qb = qh + (b * 2048) * 1024 + h * 64;
    const u16* kb = kh + (b * 2048) * 1024 + h * 64;
    const u16* vb = vh + (by * 64) * 2048;
    u16* sPw = sP + w * 16 * 72;
    const int tl = w * 16 + l15;        // t col owned by this lane
    // staging: chunk c -> (row=c>>3, col=(c&7)*8), two chunks per thread
    const int c0 = tid, c1 = 256 + tid;
    const int r0c = c0 >> 3, o0c = (c0 & 7) * 8;
    const int r1c = c1 >> 3, o1c = (c1 & 7) * 8;
    u16* sKd0 = sK + (o0c >> 5) * 2048 + r0c * 32 + (o0c & 31);
    u16* sKd1 = sK + (o1c >> 5) * 2048 + r1c * 32 + (o1c & 31);
    u16* sVd0 = sV + (o0c >> 5) * 2048 + r0c * 32 + (o0c & 31);
    u16* sVd1 = sV + (o1c >> 5) * 2048 + r1c * 32 + (o1c & 31);
    const u16* kg0 = kb + r0c * 1024 + o0c;    // + jt*65536
    const u16* kg1 = kb + r1c * 1024 + o1c;
    const u16* vg0 = vb + r0c * 2048 + o0c;    // + jt*64
    const u16* vg1 = vb + r1c * 2048 + o1c;

    for (int hv = 0; hv < 2; ++hv) {
        const int qt = hv ? p : 31 - p;
        const int tg = qt * 64 + tl;
        bf16x8 aq[2];
        aq[0] = *(const bf16x8*)(qb + tg * 1024 + quad * 8);
        aq[1] = *(const bf16x8*)(qb + tg * 1024 + 32 + quad * 8);
        f32x4 oacc[4] = {};
        float mrow = -3e38f, lrow = 0.f;
        uint4 kr0 = *(const uint4*)(kg0);
        uint4 kr1 = *(const uint4*)(kg1);
        uint4 vr0 = *(const uint4*)(vg0);
        uint4 vr1 = *(const uint4*)(vg1);
        for (int jt = 0; jt <= qt; ++jt) {
            __syncthreads();           // prev iter's LDS consumers done
            *(uint4*)sKd0 = kr0; *(uint4*)sKd1 = kr1;
            *(uint4*)sVd0 = vr0; *(uint4*)sVd1 = vr1;
            __syncthreads();
            if (jt < qt) {             // prefetch next K/V tile (covers global latency)
                kr0 = *(const uint4*)(kg0 + (jt + 1) * 65536);
                kr1 = *(const uint4*)(kg1 + (jt + 1) * 65536);
                vr0 = *(const uint4*)(vg0 + (jt + 1) * 64);
                vr1 = *(const uint4*)(vg1 + (jt + 1) * 64);
            }
            // S^T = K Q^T: rows s (regs), cols t (lanes)
            f32x4 sacc[4] = {};
#pragma unroll
            for (int j4 = 0; j4 < 4; ++j4)
#pragma unroll
                for (int k2 = 0; k2 < 2; ++k2) {
                    bf16x8 ak = *(const bf16x8*)(sK + k2 * 2048 + (j4 * 16 + l15) * 32 + quad * 8);
                    sacc[j4] = __builtin_amdgcn_mfma_f32_16x16x32_bf16(ak, aq[k2], sacc[j4], 0, 0, 0);
                }
            if (jt == qt) {            // diagonal: s > t -> -inf
#pragma unroll
                for (int j4 = 0; j4 < 4; ++j4)
#pragma unroll
                    for (int r = 0; r < 4; ++r)
                        if (j4 * 16 + quad * 4 + r > tl) sacc[j4][r] = -1e30f;
            }
            // online softmax: 16 s-values in-lane + quad butterfly (xor 16,32)
            float mx = -3e38f;
#pragma unroll
            for (int j4 = 0; j4 < 4; ++j4)
#pragma unroll
                for (int r = 0; r < 4; ++r) mx = fmaxf(mx, sacc[j4][r]);
            mx = fmaxf(mx, __shfl_xor(mx, 16));
            mx = fmaxf(mx, __shfl_xor(mx, 32));
            float mnew = fmaxf(mrow, mx);
            float alpha = __builtin_amdgcn_exp2f(mrow - mnew);
            float rs = 0.f;
#pragma unroll
            for (int j4 = 0; j4 < 4; ++j4)
#pragma unroll
                for (int r = 0; r < 4; ++r) {
                    float pe = __builtin_amdgcn_exp2f(sacc[j4][r] - mnew);
                    sacc[j4][r] = pe; rs += pe;
                }
            rs += __shfl_xor(rs, 16);
            rs += __shfl_xor(rs, 32);
            lrow = lrow * alpha + rs;
            mrow = mnew;
#pragma unroll
            for (int e4 = 0; e4 < 4; ++e4) {
                oacc[e4][0] *= alpha; oacc[e4][1] *= alpha;
                oacc[e4][2] *= alpha; oacc[e4][3] *= alpha;
            }
            // P^T: packed b64 writes to per-wave strip, read back as B-frag
#pragma unroll
            for (int j4 = 0; j4 < 4; ++j4) {
                ushort4 o;
                o.x = f2bf(sacc[j4][0]); o.y = f2bf(sacc[j4][1]);
                o.z = f2bf(sacc[j4][2]); o.w = f2bf(sacc[j4][3]);
                *(ushort4*)(sPw + l15 * 72 + j4 * 16 + quad * 4) = o;
            }
            bf16x8 bp[2];
            bp[0] = *(const bf16x8*)(sPw + l15 * 72 + quad * 8);
            bp[1] = *(const bf16x8*)(sPw + l15 * 72 + 32 + quad * 8);
            // O^T += V^T P^T
#pragma unroll
            for (int e4 = 0; e4 < 4; ++e4)
#pragma unroll
                for (int k2 = 0; k2 < 2; ++k2) {
                    bf16x8 av = *(const bf16x8*)(sV + k2 * 2048 + (e4 * 16 + l15) * 32 + quad * 8);
                    oacc[e4] = __builtin_amdgcn_mfma_f32_16x16x32_bf16(av, bp[k2], oacc[e4], 0, 0, 0);
                }
        }
        // epilogue: O^T col t = lane; e contiguous in regs -> ushort4 stores
        float inv = 1.f / lrow;
        u16* orow = ot + (b * 2048 + tg) * 1024 + h * 64;
#pragma unroll
        for (int e4 = 0; e4 < 4; ++e4) {
            ushort4 o;
            o.x = f2bf(oacc[e4][0] * inv); o.y = f2bf(oacc[e4][1] * inv);
            o.z = f2bf(oacc[e4][2] * inv); o.w = f2bf(oacc[e4][3] * inv);
            *(ushort4*)(orow + e4 * 16 + quad * 4) = o;
        }
    }
}

// ---------------- kernel 5: out = ot[M,1024] @ Wu + bu ----------------
__global__ __launch_bounds__(256) void gemm_out(const u16* __restrict__ ot, const u16* __restrict__ wut,
                                                const float* __restrict__ bu, float* __restrict__ out) {
    __shared__ float red[4][1088];     // [w][n*17 + m]
    int tid = threadIdx.x, lane = tid & 63, w = tid >> 6;
    int quad = lane >> 4, l15 = lane & 15;
    int m0 = blockIdx.x * 16;
    f32x4 acc[4] = {};
    const u16* aptr = ot + (m0 + l15) * 1024 + w * 256 + quad * 8;
    const u16* bptr = wut + l15 * 1024 + w * 256 + quad * 8;
#pragma unroll
    for (int kk = 0; kk < 8; ++kk) {
        bf16x8 af = *(const bf16x8*)(aptr + kk * 32);
#pragma unroll
        for (int j = 0; j < 4; ++j) {
            bf16x8 bfr = *(const bf16x8*)(bptr + j * 16 * 1024 + kk * 32);
            acc[j] = __builtin_amdgcn_mfma_f32_16x16x32_bf16(af, bfr, acc[j], 0, 0, 0);
        }
    }
#pragma unroll
    for (int j = 0; j < 4; ++j)
#pragma unroll
        for (int r = 0; r < 4; ++r)
            red[w][(j * 16 + l15) * 17 + quad * 4 + r] = acc[j][r];
    __syncthreads();
    int n = tid & 63, mq = tid >> 6;
    float bias = bu[n];
#pragma unroll
    for (int i = 0; i < 4; ++i) {
        int m = mq * 4 + i;
        float s = red[0][n * 17 + m] + red[1][n * 17 + m] + red[2][n * 17 + m] + red[3][n * 17 + m];
        out[(m0 + m) * 64 + n] = s + bias;
    }
}

// ---------------- workspace layout (bytes) ----------------
#define OFF_XB   0u          /* 8 MB; ot aliases this (xb dead after gemm_qkv) */
#define OFF_WQT  8388608u    /* wqt/wkt/wvt contiguous = W3[3072][1024] */
#define OFF_WUT  14680064u   /* 128 KB */
#define OFF_QH   14811136u   /* 8 MB each */
#define OFF_KH   23199744u
#define OFF_VH   31588352u
#define OFF_OT   OFF_XB

extern "C" void kernel_launch(void* const* d_in, const int* in_sizes, int n_in,
                              void* d_out, int out_size, void* d_ws, size_t ws_size,
                              hipStream_t stream) {
    (void)in_sizes; (void)n_in; (void)out_size; (void)ws_size;
    const float* inp = (const float*)d_in[0];
    // d_in[1] = causal mask — implemented analytically
    const float* Wq = (const float*)d_in[2];
    const float* Wk = (const float*)d_in[3];
    const float* Wv = (const float*)d_in[4];
    const float* Wu = (const float*)d_in[5];
    const float* bu = (const float*)d_in[6];
    float* out = (float*)d_out;
    char* ws = (char*)d_ws;
    u16* xb  = (u16*)(ws + OFF_XB);
    u16* wqt = (u16*)(ws + OFF_WQT);
    u16* wkt = wqt + 1024 * 1024;
    u16* wvt = wqt + 2048 * 1024;
    u16* wut = (u16*)(ws + OFF_WUT);
    u16* qh  = (u16*)(ws + OFF_QH);
    u16* kh  = (u16*)(ws + OFF_KH);
    u16* vh  = (u16*)(ws + OFF_VH);
    u16* ot  = (u16*)(ws + OFF_OT);

    cast_x<<<4096, 256, 0, stream>>>(inp, xb, (MM * 1024) / 4);
    transpose_w<<<dim3(32, 32, 4), 256, 0, stream>>>(Wq, Wk, Wv, Wu, wqt, wkt, wvt, wut);
    gemm_qkv<<<dim3(24, 32), 256, 0, stream>>>(xb, wqt, qh, kh, vh);
    attn<<<dim3(32, 16), 256, 0, stream>>>(qh, kh, vh, ot);
    gemm_out<<<256, 256, 0, stream>>>(ot, wut, bu, out);
}